// Round 7
// baseline (237.619 us; speedup 1.0000x reference)
//
#include <hip/hip_runtime.h>
#include <hip/hip_bf16.h>

#define N_NODES 50000
#define NP1     50001
#define N_EDGES 800000
#define NFEAT   256
#define NHID    64
#define HEADS   4
#define NCLASS  16
#define NEG_SLOPE 0.2f

#define NBLK  782                 // edge blocks (1024 edges each)
#define NBUCK 196                 // buckets of 256 nodes (dst >> 8)
#define NSCAN (NBUCK * NBLK)      // 153272
#define NSCB  150                 // ceil(NSCAN / 1024)
#define MAXB  5120                // max edges per bucket (avg 4096)
#define NGB   391                 // gemm1 blocks: (N_NODES+127)/128

typedef __attribute__((ext_vector_type(8))) short short8;
typedef __attribute__((ext_vector_type(4))) float floatx4;
typedef __attribute__((ext_vector_type(2))) float floatx2;

__device__ __forceinline__ float blo(unsigned int u) { return __uint_as_float(u << 16); }
__device__ __forceinline__ float bhi(unsigned int u) { return __uint_as_float(u & 0xffff0000u); }
__device__ __forceinline__ float b2f(unsigned short u) {
    return __uint_as_float(((unsigned int)u) << 16);
}
__device__ __forceinline__ unsigned short f2b(float f) {
    unsigned int x = __float_as_uint(f);
    unsigned int r = x + 0x7fffu + ((x >> 16) & 1u);
    return (unsigned short)(r >> 16);
}
__device__ __forceinline__ unsigned int pack2(float a, float b) {
    return (unsigned int)f2b(a) | ((unsigned int)f2b(b) << 16);
}
__device__ __forceinline__ float leaky(float x) { return fmaxf(x, NEG_SLOPE * x); }

// fp8 unpack + packed-fp32 accumulate: 8 cvt_pk + 8 v_pk_fma_f32 per 16 features
__device__ __forceinline__ void fp8acc2(uint4 u, floatx2 exv, floatx2* acc) {
    acc[0] = __builtin_elementwise_fma(__builtin_amdgcn_cvt_pk_f32_fp8(u.x, 0), exv, acc[0]);
    acc[1] = __builtin_elementwise_fma(__builtin_amdgcn_cvt_pk_f32_fp8(u.x, 1), exv, acc[1]);
    acc[2] = __builtin_elementwise_fma(__builtin_amdgcn_cvt_pk_f32_fp8(u.y, 0), exv, acc[2]);
    acc[3] = __builtin_elementwise_fma(__builtin_amdgcn_cvt_pk_f32_fp8(u.y, 1), exv, acc[3]);
    acc[4] = __builtin_elementwise_fma(__builtin_amdgcn_cvt_pk_f32_fp8(u.z, 0), exv, acc[4]);
    acc[5] = __builtin_elementwise_fma(__builtin_amdgcn_cvt_pk_f32_fp8(u.z, 1), exv, acc[5]);
    acc[6] = __builtin_elementwise_fma(__builtin_amdgcn_cvt_pk_f32_fp8(u.w, 0), exv, acc[6]);
    acc[7] = __builtin_elementwise_fma(__builtin_amdgcn_cvt_pk_f32_fp8(u.w, 1), exv, acc[7]);
}

// ---------------- P1: per-block bucket histogram + fused weight prep ----------------
__global__ __launch_bounds__(256) void p1_kernel(
        const int* __restrict__ dst, int* __restrict__ bhist,
        const float* __restrict__ W1, const float* __restrict__ W2,
        const float* __restrict__ al1, const float* __restrict__ ar1,
        unsigned short* __restrict__ W1E, unsigned short* __restrict__ W2T) {
    __shared__ float tile[64][65];
    __shared__ int hist[NBUCK];
    int b = blockIdx.x, t = threadIdx.x;
    if (b < NBLK) {
        if (t < NBUCK) hist[t] = 0;
        __syncthreads();
        int e = (b * 256 + t) * 4;
        if (e < N_EDGES) {
            int4 d = *(const int4*)&dst[e];
            atomicAdd(&hist[d.x >> 8], 1);
            atomicAdd(&hist[d.y >> 8], 1);
            atomicAdd(&hist[d.z >> 8], 1);
            atomicAdd(&hist[d.w >> 8], 1);
        }
        __syncthreads();
        if (t < NBUCK) bhist[t * NBLK + b] = hist[t];
        return;
    }
    int pb = b - NBLK;
    if (pb < 16) {
        int tk = (pb & 3) * 64, tn = (pb >> 2) * 64;
        int tx = t & 63, ty = t >> 6;
#pragma unroll
        for (int r = 0; r < 16; ++r) {
            int row = ty * 16 + r;
            tile[row][tx] = W1[(tk + row) * 256 + tn + tx];
        }
        __syncthreads();
#pragma unroll
        for (int r = 0; r < 16; ++r) {
            int row = ty * 16 + r;
            W1E[(tn + row) * 256 + tk + tx] = f2b(tile[tx][row]);
        }
    } else if (pb < 20) {
        int h = pb - 16;
        int w = t >> 6, lane = t & 63;
        float alv = al1[h * 64 + lane];
        float arv = ar1[h * 64 + lane];
        for (int k = w; k < 256; k += 4) {
            float wv = W1[k * 256 + h * 64 + lane];
            float sl = wv * alv, sr = wv * arv;
#pragma unroll
            for (int off = 1; off < 64; off <<= 1) {
                sl += __shfl_xor(sl, off);
                sr += __shfl_xor(sr, off);
            }
            if (lane == 0) {
                W1E[(256 + h) * 256 + k] = f2b(sl);
                W1E[(260 + h) * 256 + k] = f2b(sr);
            }
        }
    } else {
        int n = t >> 4, k0 = (t & 15) * 16;
#pragma unroll
        for (int j = 0; j < 16; ++j)
            W2T[n * 256 + k0 + j] = f2b(W2[(k0 + j) * 16 + n]);
#pragma unroll
        for (int j = 0; j < 8; ++j)
            W1E[264 * 256 + j * 256 + t] = 0;
    }
}

// ---------------- scanA: per-chunk (1024) exclusive scan of bhist ----------------
__global__ __launch_bounds__(256) void scanA_kernel(const int* __restrict__ bhist,
                                                    int* __restrict__ partial,
                                                    int* __restrict__ bsum) {
    __shared__ int wsum[4];
    int t = threadIdx.x;
    int base = blockIdx.x * 1024 + t * 4;
    int v0 = (base + 0 < NSCAN) ? bhist[base + 0] : 0;
    int v1 = (base + 1 < NSCAN) ? bhist[base + 1] : 0;
    int v2 = (base + 2 < NSCAN) ? bhist[base + 2] : 0;
    int v3 = (base + 3 < NSCAN) ? bhist[base + 3] : 0;
    int s = v0 + v1 + v2 + v3;
    int lane = t & 63, w = t >> 6;
    int incl = s;
#pragma unroll
    for (int off = 1; off < 64; off <<= 1) {
        int x = __shfl_up(incl, off);
        if (lane >= off) incl += x;
    }
    if (lane == 63) wsum[w] = incl;
    __syncthreads();
    int woff = 0;
    for (int k = 0; k < w; ++k) woff += wsum[k];
    int excl = woff + incl - s;
    if (base + 0 < NSCAN) partial[base + 0] = excl;
    if (base + 1 < NSCAN) partial[base + 1] = excl + v0;
    if (base + 2 < NSCAN) partial[base + 2] = excl + v0 + v1;
    if (base + 3 < NSCAN) partial[base + 3] = excl + v0 + v1 + v2;
    if (t == 255) bsum[blockIdx.x] = woff + incl;
}

// ---------------- P2+GEMM1 merged dispatch ----------------
// blocks [0, NGB): gemm1 (MFMA-heavy);  blocks [NGB, NGB+NBLK): p2 edge presort
__global__ __launch_bounds__(256, 2) void p2g1_kernel(
        const int* __restrict__ src, const int* __restrict__ dst,
        const int* __restrict__ partial, const int* __restrict__ bsum,
        unsigned int* __restrict__ ebuf,
        const float* __restrict__ X, const unsigned short* __restrict__ BT,
        unsigned char* __restrict__ C, float* __restrict__ el, float* __restrict__ er) {
    // gemm1 LDS
    __shared__ __align__(16) unsigned short As[128 * 40];
    __shared__ __align__(16) unsigned short Bs[272 * 40];
    // p2 LDS
    __shared__ int wsum[4];
    __shared__ int sb[256];
    __shared__ int bs[NBUCK];
    __shared__ int lcnt[256];
    __shared__ int lofs[256];
    __shared__ int lfill[256];
    __shared__ unsigned int sorted[1024];

    int t = threadIdx.x;
    if (blockIdx.x >= NGB) {
        // ---- p2: LDS bucket presort ----
        int b = blockIdx.x - NGB;
        int lane = t & 63, w = t >> 6;
        {
            int v = (t < NSCB) ? bsum[t] : 0;
            int incl = v;
#pragma unroll
            for (int off = 1; off < 64; off <<= 1) {
                int x = __shfl_up(incl, off);
                if (lane >= off) incl += x;
            }
            if (lane == 63) wsum[w] = incl;
            __syncthreads();
            int woff = 0;
            for (int k = 0; k < w; ++k) woff += wsum[k];
            sb[t] = woff + incl - v;
        }
        lcnt[t] = 0;
        __syncthreads();
        if (t < NBUCK) {
            int idx = t * NBLK + b;
            bs[t] = partial[idx] + sb[idx >> 10];
        }
        int e = (b * 256 + t) * 4;
        int4 d, s;
        bool valid = e < N_EDGES;
        if (valid) {
            d = *(const int4*)&dst[e];
            s = *(const int4*)&src[e];
            atomicAdd(&lcnt[d.x >> 8], 1);
            atomicAdd(&lcnt[d.y >> 8], 1);
            atomicAdd(&lcnt[d.z >> 8], 1);
            atomicAdd(&lcnt[d.w >> 8], 1);
        }
        __syncthreads();
        {
            int v = lcnt[t];
            int incl = v;
#pragma unroll
            for (int off = 1; off < 64; off <<= 1) {
                int x = __shfl_up(incl, off);
                if (lane >= off) incl += x;
            }
            if (lane == 63) wsum[w] = incl;
            __syncthreads();
            int woff = 0;
            for (int k = 0; k < w; ++k) woff += wsum[k];
            int excl = woff + incl - v;
            lofs[t] = excl;
            lfill[t] = excl;
        }
        __syncthreads();
        if (valid) {
            int p0 = atomicAdd(&lfill[d.x >> 8], 1);
            sorted[p0] = ((unsigned int)s.x << 16) | (unsigned int)d.x;
            int p1 = atomicAdd(&lfill[d.y >> 8], 1);
            sorted[p1] = ((unsigned int)s.y << 16) | (unsigned int)d.y;
            int p2 = atomicAdd(&lfill[d.z >> 8], 1);
            sorted[p2] = ((unsigned int)s.z << 16) | (unsigned int)d.z;
            int p3 = atomicAdd(&lfill[d.w >> 8], 1);
            sorted[p3] = ((unsigned int)s.w << 16) | (unsigned int)d.w;
        }
        __syncthreads();
        int ve = min(1024, N_EDGES - b * 1024);
        for (int i = t; i < ve; i += 256) {
            unsigned int p = sorted[i];
            int k = (p & 0xFFFFu) >> 8;
            ebuf[bs[k] + (i - lofs[k])] = p;
        }
        return;
    }

    // ---- gemm1: [feat1(fp8) | el | er] = x @ [W1 | Wel | Wer] ----
    int m0 = blockIdx.x * 128;
    int lane = t & 63, wm = t >> 6;
    int quad = lane >> 4, l16 = lane & 15;

    floatx4 acc[2][17];
#pragma unroll
    for (int i = 0; i < 2; ++i)
#pragma unroll
        for (int j = 0; j < 17; ++j) acc[i][j] = (floatx4){0.f, 0.f, 0.f, 0.f};

    int arow = t >> 1, ak = (t & 1) * 16;
    int grow = m0 + arow;
    const float* xrow = X + (size_t)grow * 256 + ak;

    for (int k0 = 0; k0 < 256; k0 += 32) {
        float4 v0 = make_float4(0.f, 0.f, 0.f, 0.f), v1 = v0, v2 = v0, v3 = v0;
        if (grow < N_NODES) {
            v0 = *(const float4*)(xrow + k0 + 0);
            v1 = *(const float4*)(xrow + k0 + 4);
            v2 = *(const float4*)(xrow + k0 + 8);
            v3 = *(const float4*)(xrow + k0 + 12);
        }
        uint4 p0, p1;
        p0.x = pack2(v0.x, v0.y); p0.y = pack2(v0.z, v0.w);
        p0.z = pack2(v1.x, v1.y); p0.w = pack2(v1.z, v1.w);
        p1.x = pack2(v2.x, v2.y); p1.y = pack2(v2.z, v2.w);
        p1.z = pack2(v3.x, v3.y); p1.w = pack2(v3.z, v3.w);
        *(uint4*)&As[arow * 40 + ak] = p0;
        *(uint4*)&As[arow * 40 + ak + 8] = p1;
#pragma unroll
        for (int i = 0; i < 5; ++i) {
            int ch = t + i * 256;
            if (ch < 1088) {
                int row = ch >> 2, off = (ch & 3) * 8;
                *(uint4*)&Bs[row * 40 + off] = *(const uint4*)(BT + row * 256 + k0 + off);
            }
        }
        __syncthreads();

        short8 a0 = *(const short8*)&As[(wm * 32 + l16) * 40 + quad * 8];
        short8 a1 = *(const short8*)&As[(wm * 32 + 16 + l16) * 40 + quad * 8];
#pragma unroll
        for (int nf = 0; nf < 17; ++nf) {
            short8 bb = *(const short8*)&Bs[(nf * 16 + l16) * 40 + quad * 8];
            acc[0][nf] = __builtin_amdgcn_mfma_f32_16x16x32_bf16(a0, bb, acc[0][nf], 0, 0, 0);
            acc[1][nf] = __builtin_amdgcn_mfma_f32_16x16x32_bf16(a1, bb, acc[1][nf], 0, 0, 0);
        }
        __syncthreads();
    }

#pragma unroll
    for (int mf = 0; mf < 2; ++mf) {
#pragma unroll
        for (int r = 0; r < 4; ++r) {
            int row = m0 + wm * 32 + mf * 16 + quad * 4 + r;
            if (row < N_NODES && l16 < 8) {
                float v = acc[mf][16][r];
                if (l16 < 4) el[row * 4 + l16] = v;
                else er[row * 4 + (l16 - 4)] = v;
            }
        }
    }

    unsigned short* scr = Bs + wm * 1536;
    int half = lane >> 5, l32 = lane & 31;
    int rrow = l32 >> 1, coff = (l32 & 1) * 8;
#pragma unroll
    for (int mf = 0; mf < 2; ++mf) {
#pragma unroll
        for (int p = 0; p < 8; ++p) {
            unsigned short* base = scr + (p & 1) * 768;
#pragma unroll
            for (int fr = 0; fr < 2; ++fr) {
                int nf = 2 * p + fr;
                unsigned short* fb = base + fr * 384;
#pragma unroll
                for (int r = 0; r < 4; ++r)
                    fb[(quad * 4 + r) * 24 + l16] = f2b(acc[mf][nf][r]);
            }
            uint4 val = *(const uint4*)(base + half * 384 + rrow * 24 + coff);
            int row = m0 + wm * 32 + mf * 16 + rrow;
            int nf = 2 * p + half;
            if (row < N_NODES) {
                float f0 = blo(val.x), f1 = bhi(val.x), f2 = blo(val.y), f3 = bhi(val.y);
                float f4 = blo(val.z), f5 = bhi(val.z), f6 = blo(val.w), f7 = bhi(val.w);
                int lo = __builtin_amdgcn_cvt_pk_fp8_f32(f0, f1, 0, 0);
                lo = __builtin_amdgcn_cvt_pk_fp8_f32(f2, f3, lo, 1);
                int hi = __builtin_amdgcn_cvt_pk_fp8_f32(f4, f5, 0, 0);
                hi = __builtin_amdgcn_cvt_pk_fp8_f32(f6, f7, hi, 1);
                uint2 o;
                o.x = (unsigned int)lo;
                o.y = (unsigned int)hi;
                *(uint2*)&C[(size_t)row * 256 + nf * 16 + coff] = o;
            }
        }
    }
}

// ---------------- P3: per-bucket LDS node presort -> coalesced csr_src + row_ptr ----------------
__global__ __launch_bounds__(256) void p3_kernel(const int* __restrict__ partial,
                                                 const int* __restrict__ bsum,
                                                 const unsigned int* __restrict__ ebuf,
                                                 int* __restrict__ row_ptr,
                                                 int* __restrict__ csr_src) {
    __shared__ int wsum[4];
    __shared__ int sb[256];
    __shared__ int lcnt[256];
    __shared__ int lfill[256];
    __shared__ int sorted[MAXB];
    int b = blockIdx.x, t = threadIdx.x;
    int lane = t & 63, w = t >> 6;
    {
        int v = (t < NSCB) ? bsum[t] : 0;
        int incl = v;
#pragma unroll
        for (int off = 1; off < 64; off <<= 1) {
            int x = __shfl_up(incl, off);
            if (lane >= off) incl += x;
        }
        if (lane == 63) wsum[w] = incl;
        __syncthreads();
        int woff = 0;
        for (int k = 0; k < w; ++k) woff += wsum[k];
        sb[t] = woff + incl - v;
    }
    __syncthreads();
    int i0 = b * NBLK;
    int base = partial[i0] + sb[i0 >> 10];
    int endb;
    if (b == NBUCK - 1) endb = N_EDGES;
    else {
        int i1 = (b + 1) * NBLK;
        endb = partial[i1] + sb[i1 >> 10];
    }
    lcnt[t] = 0;
    __syncthreads();
    for (int i = base + t; i < endb; i += 256)
        atomicAdd(&lcnt[ebuf[i] & 255u], 1);
    __syncthreads();
    {
        int v = lcnt[t];
        int incl = v;
#pragma unroll
        for (int off = 1; off < 64; off <<= 1) {
            int x = __shfl_up(incl, off);
            if (lane >= off) incl += x;
        }
        if (lane == 63) wsum[w] = incl;
        __syncthreads();
        int woff = 0;
        for (int k = 0; k < w; ++k) woff += wsum[k];
        int excl = woff + incl - v;
        lfill[t] = excl;
        int node = b * 256 + t;
        if (node < NP1) row_ptr[node] = base + excl;
    }
    __syncthreads();
    for (int i = base + t; i < endb; i += 256) {
        unsigned int p = ebuf[i];
        int pos = atomicAdd(&lfill[p & 255u], 1);
        sorted[pos] = (int)(p >> 16);
    }
    __syncthreads();
    int M = endb - base;
    for (int i = t; i < M; i += 256)
        csr_src[base + i] = sorted[i];
}

// ---------------- layer-1 aggregation: 4 nodes/wave, no cross-lane reduce, 4-deep MLP ----------------
// Each 16-lane group (q = lane>>4) owns node n and its FULL 256B feat row (lane l16 covers
// features l16*16..+16, head h = l16>>2). Edges walked sequentially, 4-deep (doubles
// feat-row fetches in flight vs R5's 2-deep to hide L3 gather latency); accumulation
// sequence and denom pairing identical to 2-deep -> bit-identical numerics.
__global__ void agg1_kernel(const unsigned char* __restrict__ feat1,
                            const float* __restrict__ el, const float* __restrict__ er,
                            const int* __restrict__ row_ptr, const int* __restrict__ csr_src,
                            const float* __restrict__ b1, unsigned short* __restrict__ h1b) {
    int wave = threadIdx.x >> 6, lane = threadIdx.x & 63;
    int q = lane >> 4, l16 = lane & 15;
    int n = (blockIdx.x * 4 + wave) * 4 + q;      // 16 nodes per block
    bool vn = n < N_NODES;
    int h = l16 >> 2;
    int start = 0, end = 0;
    if (vn) {
        start = row_ptr[n];
        end = row_ptr[n + 1];
    }
    float er_h = vn ? er[n * 4 + h] : 0.f;

    floatx2 acc2[8];
#pragma unroll
    for (int j = 0; j < 8; ++j) acc2[j] = (floatx2){0.f, 0.f};
    float denom = 0.f;

    int i = start;
    for (; i + 3 < end; i += 4) {
        int s0 = csr_src[i];
        int s1 = csr_src[i + 1];
        int s2 = csr_src[i + 2];
        int s3 = csr_src[i + 3];
        float e0 = __expf(leaky(el[s0 * 4 + h] + er_h));
        float e1 = __expf(leaky(el[s1 * 4 + h] + er_h));
        float e2 = __expf(leaky(el[s2 * 4 + h] + er_h));
        float e3 = __expf(leaky(el[s3 * 4 + h] + er_h));
        uint4 a = *(const uint4*)(feat1 + (size_t)s0 * 256 + l16 * 16);
        uint4 b = *(const uint4*)(feat1 + (size_t)s1 * 256 + l16 * 16);
        uint4 c = *(const uint4*)(feat1 + (size_t)s2 * 256 + l16 * 16);
        uint4 d = *(const uint4*)(feat1 + (size_t)s3 * 256 + l16 * 16);
        denom += e0 + e1;
        denom += e2 + e3;
        fp8acc2(a, (floatx2){e0, e0}, acc2);
        fp8acc2(b, (floatx2){e1, e1}, acc2);
        fp8acc2(c, (floatx2){e2, e2}, acc2);
        fp8acc2(d, (floatx2){e3, e3}, acc2);
    }
    for (; i + 1 < end; i += 2) {
        int s0 = csr_src[i];
        int s1 = csr_src[i + 1];
        float e0 = __expf(leaky(el[s0 * 4 + h] + er_h));
        float e1 = __expf(leaky(el[s1 * 4 + h] + er_h));
        uint4 a = *(const uint4*)(feat1 + (size_t)s0 * 256 + l16 * 16);
        uint4 b = *(const uint4*)(feat1 + (size_t)s1 * 256 + l16 * 16);
        denom += e0 + e1;
        fp8acc2(a, (floatx2){e0, e0}, acc2);
        fp8acc2(b, (floatx2){e1, e1}, acc2);
    }
    if (i < end) {
        int s = csr_src[i];
        float e = __expf(leaky(el[s * 4 + h] + er_h));
        uint4 u = *(const uint4*)(feat1 + (size_t)s * 256 + l16 * 16);
        denom += e;
        fp8acc2(u, (floatx2){e, e}, acc2);
    }
    if (!vn) return;

    float inv = (end > start) ? 1.f / denom : 0.f;
    float o[16];
#pragma unroll
    for (int j = 0; j < 8; ++j) {
        o[2 * j] = acc2[j][0];
        o[2 * j + 1] = acc2[j][1];
    }
#pragma unroll
    for (int j = 0; j < 16; j += 4) {
        float4 b4 = *(const float4*)&b1[l16 * 16 + j];
        o[j + 0] = fmaf(o[j + 0], inv, b4.x);
        o[j + 1] = fmaf(o[j + 1], inv, b4.y);
        o[j + 2] = fmaf(o[j + 2], inv, b4.z);
        o[j + 3] = fmaf(o[j + 3], inv, b4.w);
    }
#pragma unroll
    for (int j = 0; j < 16; ++j) o[j] = o[j] > 0.f ? o[j] : __expf(o[j]) - 1.f;
    uint4 pa, pb;
    pa.x = pack2(o[0], o[1]);   pa.y = pack2(o[2], o[3]);
    pa.z = pack2(o[4], o[5]);   pa.w = pack2(o[6], o[7]);
    pb.x = pack2(o[8], o[9]);   pb.y = pack2(o[10], o[11]);
    pb.z = pack2(o[12], o[13]); pb.w = pack2(o[14], o[15]);
    uint4* dstp = (uint4*)(h1b + (size_t)n * 256 + l16 * 16);
    dstp[0] = pa;
    dstp[1] = pb;
}

// ---------------- GEMM2 (bf16 MFMA, no LDS) + fused el2/er2, bf16 feat2 out ----------------
__global__ __launch_bounds__(256) void gemm2_mfma_kernel(
        const unsigned short* __restrict__ h1b, const unsigned short* __restrict__ W2T,
        const float* __restrict__ al2, const float* __restrict__ ar2,
        unsigned short* __restrict__ feat2b, float* __restrict__ el2, float* __restrict__ er2) {
    int wave = threadIdx.x >> 6, lane = threadIdx.x & 63;
    int l16 = lane & 15, quad = lane >> 4;
    int row0 = (blockIdx.x * 4 + wave) * 16;
    if (row0 >= N_NODES) return;
    floatx4 acc = (floatx4){0.f, 0.f, 0.f, 0.f};
    const unsigned short* arow = h1b + (size_t)(row0 + l16) * 256 + quad * 8;
    const unsigned short* brow = W2T + (size_t)l16 * 256 + quad * 8;
#pragma unroll
    for (int k0 = 0; k0 < 256; k0 += 32) {
        short8 a = *(const short8*)(arow + k0);
        short8 b = *(const short8*)(brow + k0);
        acc = __builtin_amdgcn_mfma_f32_16x16x32_bf16(a, b, acc, 0, 0, 0);
    }
    float a2 = al2[l16], r2 = ar2[l16];
#pragma unroll
    for (int r = 0; r < 4; ++r) {
        int row = row0 + quad * 4 + r;
        float v = acc[r];
        feat2b[row * 16 + l16] = f2b(v);
        float pl = v * a2, pr = v * r2;
#pragma unroll
        for (int off = 1; off < 16; off <<= 1) {
            pl += __shfl_xor(pl, off);
            pr += __shfl_xor(pr, off);
        }
        if (l16 == 0) {
            el2[row] = pl;
            er2[row] = pr;
        }
    }
}

// ---------------- layer-2 aggregation + log_softmax: 4 nodes/wave, no cross-quad reduce ----------------
__global__ void agg2_kernel(const unsigned short* __restrict__ feat2b,
                            const float* __restrict__ el2, const float* __restrict__ er2,
                            const int* __restrict__ row_ptr, const int* __restrict__ csr_src,
                            const float* __restrict__ b2, float* __restrict__ out) {
    int wave = threadIdx.x >> 6, lane = threadIdx.x & 63;
    int q = lane >> 4, c = lane & 15;
    int n = (blockIdx.x * 4 + wave) * 4 + q;      // 16 nodes per block
    if (n >= N_NODES) return;
    int start = row_ptr[n], end = row_ptr[n + 1];
    float ern = er2[n];
    float acc = 0.f, denom = 0.f;
    int i = start;
    for (; i + 1 < end; i += 2) {
        int s0 = csr_src[i], s1 = csr_src[i + 1];
        float e0 = __expf(leaky(el2[s0] + ern));
        float e1 = __expf(leaky(el2[s1] + ern));
        float f0 = b2f(feat2b[s0 * 16 + c]), f1 = b2f(feat2b[s1 * 16 + c]);
        denom += e0 + e1;
        acc = fmaf(f0, e0, acc);
        acc = fmaf(f1, e1, acc);
    }
    if (i < end) {
        int s = csr_src[i];
        float e = __expf(leaky(el2[s] + ern));
        denom += e;
        acc = fmaf(b2f(feat2b[s * 16 + c]), e, acc);
    }
    float v = ((end > start) ? acc / denom : 0.f) + b2[c];
    float mx = v;
#pragma unroll
    for (int off = 1; off < 16; off <<= 1) mx = fmaxf(mx, __shfl_xor(mx, off));
    float ex2 = __expf(v - mx);
    float s2 = ex2;
#pragma unroll
    for (int off = 1; off < 16; off <<= 1) s2 += __shfl_xor(s2, off);
    float res = v - mx - logf(s2);
    out[n * 16 + c] = res;
}

// ---------------- launch ----------------
extern "C" void kernel_launch(void* const* d_in, const int* in_sizes, int n_in,
                              void* d_out, int out_size, void* d_ws, size_t ws_size,
                              hipStream_t stream) {
    const float* x   = (const float*)d_in[0];
    const int*   src = (const int*)d_in[1];
    const int*   dst = (const int*)d_in[2];
    const float* W1  = (const float*)d_in[3];
    const float* al1 = (const float*)d_in[4];
    const float* ar1 = (const float*)d_in[5];
    const float* b1  = (const float*)d_in[6];
    const float* W2  = (const float*)d_in[7];
    const float* al2 = (const float*)d_in[8];
    const float* ar2 = (const float*)d_in[9];
    const float* b2  = (const float*)d_in[10];
    float* out = (float*)d_out;

    char* ws = (char*)d_ws;
    size_t off = 0;
    auto alloc = [&](size_t bytes) -> void* {
        void* p = ws + off;
        off += (bytes + 255) & ~(size_t)255;
        return p;
    };
    unsigned short* W1E    = (unsigned short*)alloc((size_t)272 * 256 * 2);
    unsigned short* W2T    = (unsigned short*)alloc((size_t)16 * 256 * 2);
    unsigned char*  feat1  = (unsigned char*)alloc((size_t)N_NODES * 256);
    unsigned short* h1b    = (unsigned short*)alloc((size_t)N_NODES * 256 * 2);
    unsigned short* feat2b = (unsigned short*)alloc((size_t)N_NODES * 16 * 2);
    float* el1     = (float*)alloc((size_t)N_NODES * 4 * 4);
    float* er1     = (float*)alloc((size_t)N_NODES * 4 * 4);
    float* el2     = (float*)alloc((size_t)N_NODES * 4);
    float* er2     = (float*)alloc((size_t)N_NODES * 4);
    int*   bhist   = (int*)alloc((size_t)NSCAN * 4);
    int*   partial = (int*)alloc((size_t)NSCAN * 4);
    int*   bsum    = (int*)alloc((size_t)256 * 4);
    int*   row_ptr = (int*)alloc((size_t)NP1 * 4);
    unsigned int* ebuf = (unsigned int*)alloc((size_t)N_EDGES * 4);
    int*   csr_src = (int*)alloc((size_t)N_EDGES * 4);

    dim3 b256(256);
    p1_kernel<<<NBLK + 21, b256, 0, stream>>>(dst, bhist, W1, W2, al1, ar1, W1E, W2T);
    scanA_kernel<<<NSCB, b256, 0, stream>>>(bhist, partial, bsum);
    p2g1_kernel<<<NGB + NBLK, b256, 0, stream>>>(src, dst, partial, bsum, ebuf,
                                                 x, W1E, feat1, el1, er1);
    p3_kernel<<<NBUCK, b256, 0, stream>>>(partial, bsum, ebuf, row_ptr, csr_src);

    agg1_kernel<<<(N_NODES + 15) / 16, b256, 0, stream>>>(feat1, el1, er1, row_ptr, csr_src, b1, h1b);

    gemm2_mfma_kernel<<<(N_NODES + 63) / 64, b256, 0, stream>>>(h1b, W2T, al2, ar2, feat2b, el2, er2);
    agg2_kernel<<<(N_NODES + 15) / 16, b256, 0, stream>>>(feat2b, el2, er2, row_ptr, csr_src, b2, out);
}

// Round 8
// 233.264 us; speedup vs baseline: 1.0187x; 1.0187x over previous
//
#include <hip/hip_runtime.h>
#include <hip/hip_bf16.h>

#define N_NODES 50000
#define NP1     50001
#define N_EDGES 800000
#define NFEAT   256
#define NHID    64
#define HEADS   4
#define NCLASS  16
#define NEG_SLOPE 0.2f

#define NBLK  782                 // edge blocks (1024 edges each)
#define NBUCK 196                 // buckets of 256 nodes (dst >> 8)
#define NSCAN (NBUCK * NBLK)      // 153272
#define NSCB  150                 // ceil(NSCAN / 1024)
#define MAXB  5120                // max edges per bucket (avg 4096)
#define NGB   391                 // gemm1 blocks: (N_NODES+127)/128

typedef __attribute__((ext_vector_type(8))) short short8;
typedef __attribute__((ext_vector_type(4))) float floatx4;
typedef __attribute__((ext_vector_type(2))) float floatx2;

__device__ __forceinline__ float blo(unsigned int u) { return __uint_as_float(u << 16); }
__device__ __forceinline__ float bhi(unsigned int u) { return __uint_as_float(u & 0xffff0000u); }
__device__ __forceinline__ float b2f(unsigned short u) {
    return __uint_as_float(((unsigned int)u) << 16);
}
__device__ __forceinline__ unsigned short f2b(float f) {
    unsigned int x = __float_as_uint(f);
    unsigned int r = x + 0x7fffu + ((x >> 16) & 1u);
    return (unsigned short)(r >> 16);
}
__device__ __forceinline__ unsigned int pack2(float a, float b) {
    return (unsigned int)f2b(a) | ((unsigned int)f2b(b) << 16);
}
__device__ __forceinline__ float leaky(float x) { return fmaxf(x, NEG_SLOPE * x); }

// fp8 unpack + packed-fp32 accumulate: 8 cvt_pk + 8 v_pk_fma_f32 per 16 features
__device__ __forceinline__ void fp8acc2(uint4 u, floatx2 exv, floatx2* acc) {
    acc[0] = __builtin_elementwise_fma(__builtin_amdgcn_cvt_pk_f32_fp8(u.x, 0), exv, acc[0]);
    acc[1] = __builtin_elementwise_fma(__builtin_amdgcn_cvt_pk_f32_fp8(u.x, 1), exv, acc[1]);
    acc[2] = __builtin_elementwise_fma(__builtin_amdgcn_cvt_pk_f32_fp8(u.y, 0), exv, acc[2]);
    acc[3] = __builtin_elementwise_fma(__builtin_amdgcn_cvt_pk_f32_fp8(u.y, 1), exv, acc[3]);
    acc[4] = __builtin_elementwise_fma(__builtin_amdgcn_cvt_pk_f32_fp8(u.z, 0), exv, acc[4]);
    acc[5] = __builtin_elementwise_fma(__builtin_amdgcn_cvt_pk_f32_fp8(u.z, 1), exv, acc[5]);
    acc[6] = __builtin_elementwise_fma(__builtin_amdgcn_cvt_pk_f32_fp8(u.w, 0), exv, acc[6]);
    acc[7] = __builtin_elementwise_fma(__builtin_amdgcn_cvt_pk_f32_fp8(u.w, 1), exv, acc[7]);
}

// ---------------- P1: per-block bucket histogram + fused weight prep ----------------
__global__ __launch_bounds__(256) void p1_kernel(
        const int* __restrict__ dst, int* __restrict__ bhist,
        const float* __restrict__ W1, const float* __restrict__ W2,
        const float* __restrict__ al1, const float* __restrict__ ar1,
        unsigned short* __restrict__ W1E, unsigned short* __restrict__ W2T) {
    __shared__ float tile[64][65];
    __shared__ int hist[NBUCK];
    int b = blockIdx.x, t = threadIdx.x;
    if (b < NBLK) {
        if (t < NBUCK) hist[t] = 0;
        __syncthreads();
        int e = (b * 256 + t) * 4;
        if (e < N_EDGES) {
            int4 d = *(const int4*)&dst[e];
            atomicAdd(&hist[d.x >> 8], 1);
            atomicAdd(&hist[d.y >> 8], 1);
            atomicAdd(&hist[d.z >> 8], 1);
            atomicAdd(&hist[d.w >> 8], 1);
        }
        __syncthreads();
        if (t < NBUCK) bhist[t * NBLK + b] = hist[t];
        return;
    }
    int pb = b - NBLK;
    if (pb < 16) {
        int tk = (pb & 3) * 64, tn = (pb >> 2) * 64;
        int tx = t & 63, ty = t >> 6;
#pragma unroll
        for (int r = 0; r < 16; ++r) {
            int row = ty * 16 + r;
            tile[row][tx] = W1[(tk + row) * 256 + tn + tx];
        }
        __syncthreads();
#pragma unroll
        for (int r = 0; r < 16; ++r) {
            int row = ty * 16 + r;
            W1E[(tn + row) * 256 + tk + tx] = f2b(tile[tx][row]);
        }
    } else if (pb < 20) {
        int h = pb - 16;
        int w = t >> 6, lane = t & 63;
        float alv = al1[h * 64 + lane];
        float arv = ar1[h * 64 + lane];
        for (int k = w; k < 256; k += 4) {
            float wv = W1[k * 256 + h * 64 + lane];
            float sl = wv * alv, sr = wv * arv;
#pragma unroll
            for (int off = 1; off < 64; off <<= 1) {
                sl += __shfl_xor(sl, off);
                sr += __shfl_xor(sr, off);
            }
            if (lane == 0) {
                W1E[(256 + h) * 256 + k] = f2b(sl);
                W1E[(260 + h) * 256 + k] = f2b(sr);
            }
        }
    } else {
        int n = t >> 4, k0 = (t & 15) * 16;
#pragma unroll
        for (int j = 0; j < 16; ++j)
            W2T[n * 256 + k0 + j] = f2b(W2[(k0 + j) * 16 + n]);
#pragma unroll
        for (int j = 0; j < 8; ++j)
            W1E[264 * 256 + j * 256 + t] = 0;
    }
}

// ---------------- scanA: per-chunk (1024) exclusive scan of bhist ----------------
__global__ __launch_bounds__(256) void scanA_kernel(const int* __restrict__ bhist,
                                                    int* __restrict__ partial,
                                                    int* __restrict__ bsum) {
    __shared__ int wsum[4];
    int t = threadIdx.x;
    int base = blockIdx.x * 1024 + t * 4;
    int v0 = (base + 0 < NSCAN) ? bhist[base + 0] : 0;
    int v1 = (base + 1 < NSCAN) ? bhist[base + 1] : 0;
    int v2 = (base + 2 < NSCAN) ? bhist[base + 2] : 0;
    int v3 = (base + 3 < NSCAN) ? bhist[base + 3] : 0;
    int s = v0 + v1 + v2 + v3;
    int lane = t & 63, w = t >> 6;
    int incl = s;
#pragma unroll
    for (int off = 1; off < 64; off <<= 1) {
        int x = __shfl_up(incl, off);
        if (lane >= off) incl += x;
    }
    if (lane == 63) wsum[w] = incl;
    __syncthreads();
    int woff = 0;
    for (int k = 0; k < w; ++k) woff += wsum[k];
    int excl = woff + incl - s;
    if (base + 0 < NSCAN) partial[base + 0] = excl;
    if (base + 1 < NSCAN) partial[base + 1] = excl + v0;
    if (base + 2 < NSCAN) partial[base + 2] = excl + v0 + v1;
    if (base + 3 < NSCAN) partial[base + 3] = excl + v0 + v1 + v2;
    if (t == 255) bsum[blockIdx.x] = woff + incl;
}

// ---------------- P2+GEMM1 merged dispatch ----------------
// blocks [0, NGB): gemm1 (MFMA-heavy);  blocks [NGB, NGB+NBLK): p2 edge presort
__global__ __launch_bounds__(256, 2) void p2g1_kernel(
        const int* __restrict__ src, const int* __restrict__ dst,
        const int* __restrict__ partial, const int* __restrict__ bsum,
        unsigned int* __restrict__ ebuf,
        const float* __restrict__ X, const unsigned short* __restrict__ BT,
        unsigned char* __restrict__ C, float* __restrict__ el, float* __restrict__ er) {
    // gemm1 LDS
    __shared__ __align__(16) unsigned short As[128 * 40];
    __shared__ __align__(16) unsigned short Bs[272 * 40];
    // p2 LDS
    __shared__ int wsum[4];
    __shared__ int sb[256];
    __shared__ int bs[NBUCK];
    __shared__ int lcnt[256];
    __shared__ int lofs[256];
    __shared__ int lfill[256];
    __shared__ unsigned int sorted[1024];

    int t = threadIdx.x;
    if (blockIdx.x >= NGB) {
        // ---- p2: LDS bucket presort ----
        int b = blockIdx.x - NGB;
        int lane = t & 63, w = t >> 6;
        {
            int v = (t < NSCB) ? bsum[t] : 0;
            int incl = v;
#pragma unroll
            for (int off = 1; off < 64; off <<= 1) {
                int x = __shfl_up(incl, off);
                if (lane >= off) incl += x;
            }
            if (lane == 63) wsum[w] = incl;
            __syncthreads();
            int woff = 0;
            for (int k = 0; k < w; ++k) woff += wsum[k];
            sb[t] = woff + incl - v;
        }
        lcnt[t] = 0;
        __syncthreads();
        if (t < NBUCK) {
            int idx = t * NBLK + b;
            bs[t] = partial[idx] + sb[idx >> 10];
        }
        int e = (b * 256 + t) * 4;
        int4 d, s;
        bool valid = e < N_EDGES;
        if (valid) {
            d = *(const int4*)&dst[e];
            s = *(const int4*)&src[e];
            atomicAdd(&lcnt[d.x >> 8], 1);
            atomicAdd(&lcnt[d.y >> 8], 1);
            atomicAdd(&lcnt[d.z >> 8], 1);
            atomicAdd(&lcnt[d.w >> 8], 1);
        }
        __syncthreads();
        {
            int v = lcnt[t];
            int incl = v;
#pragma unroll
            for (int off = 1; off < 64; off <<= 1) {
                int x = __shfl_up(incl, off);
                if (lane >= off) incl += x;
            }
            if (lane == 63) wsum[w] = incl;
            __syncthreads();
            int woff = 0;
            for (int k = 0; k < w; ++k) woff += wsum[k];
            int excl = woff + incl - v;
            lofs[t] = excl;
            lfill[t] = excl;
        }
        __syncthreads();
        if (valid) {
            int p0 = atomicAdd(&lfill[d.x >> 8], 1);
            sorted[p0] = ((unsigned int)s.x << 16) | (unsigned int)d.x;
            int p1 = atomicAdd(&lfill[d.y >> 8], 1);
            sorted[p1] = ((unsigned int)s.y << 16) | (unsigned int)d.y;
            int p2 = atomicAdd(&lfill[d.z >> 8], 1);
            sorted[p2] = ((unsigned int)s.z << 16) | (unsigned int)d.z;
            int p3 = atomicAdd(&lfill[d.w >> 8], 1);
            sorted[p3] = ((unsigned int)s.w << 16) | (unsigned int)d.w;
        }
        __syncthreads();
        int ve = min(1024, N_EDGES - b * 1024);
        for (int i = t; i < ve; i += 256) {
            unsigned int p = sorted[i];
            int k = (p & 0xFFFFu) >> 8;
            ebuf[bs[k] + (i - lofs[k])] = p;
        }
        return;
    }

    // ---- gemm1: [feat1(fp8) | el | er] = x @ [W1 | Wel | Wer] ----
    int m0 = blockIdx.x * 128;
    int lane = t & 63, wm = t >> 6;
    int quad = lane >> 4, l16 = lane & 15;

    floatx4 acc[2][17];
#pragma unroll
    for (int i = 0; i < 2; ++i)
#pragma unroll
        for (int j = 0; j < 17; ++j) acc[i][j] = (floatx4){0.f, 0.f, 0.f, 0.f};

    int arow = t >> 1, ak = (t & 1) * 16;
    int grow = m0 + arow;
    const float* xrow = X + (size_t)grow * 256 + ak;

    for (int k0 = 0; k0 < 256; k0 += 32) {
        float4 v0 = make_float4(0.f, 0.f, 0.f, 0.f), v1 = v0, v2 = v0, v3 = v0;
        if (grow < N_NODES) {
            v0 = *(const float4*)(xrow + k0 + 0);
            v1 = *(const float4*)(xrow + k0 + 4);
            v2 = *(const float4*)(xrow + k0 + 8);
            v3 = *(const float4*)(xrow + k0 + 12);
        }
        uint4 p0, p1;
        p0.x = pack2(v0.x, v0.y); p0.y = pack2(v0.z, v0.w);
        p0.z = pack2(v1.x, v1.y); p0.w = pack2(v1.z, v1.w);
        p1.x = pack2(v2.x, v2.y); p1.y = pack2(v2.z, v2.w);
        p1.z = pack2(v3.x, v3.y); p1.w = pack2(v3.z, v3.w);
        *(uint4*)&As[arow * 40 + ak] = p0;
        *(uint4*)&As[arow * 40 + ak + 8] = p1;
#pragma unroll
        for (int i = 0; i < 5; ++i) {
            int ch = t + i * 256;
            if (ch < 1088) {
                int row = ch >> 2, off = (ch & 3) * 8;
                *(uint4*)&Bs[row * 40 + off] = *(const uint4*)(BT + row * 256 + k0 + off);
            }
        }
        __syncthreads();

        short8 a0 = *(const short8*)&As[(wm * 32 + l16) * 40 + quad * 8];
        short8 a1 = *(const short8*)&As[(wm * 32 + 16 + l16) * 40 + quad * 8];
#pragma unroll
        for (int nf = 0; nf < 17; ++nf) {
            short8 bb = *(const short8*)&Bs[(nf * 16 + l16) * 40 + quad * 8];
            acc[0][nf] = __builtin_amdgcn_mfma_f32_16x16x32_bf16(a0, bb, acc[0][nf], 0, 0, 0);
            acc[1][nf] = __builtin_amdgcn_mfma_f32_16x16x32_bf16(a1, bb, acc[1][nf], 0, 0, 0);
        }
        __syncthreads();
    }

#pragma unroll
    for (int mf = 0; mf < 2; ++mf) {
#pragma unroll
        for (int r = 0; r < 4; ++r) {
            int row = m0 + wm * 32 + mf * 16 + quad * 4 + r;
            if (row < N_NODES && l16 < 8) {
                float v = acc[mf][16][r];
                if (l16 < 4) el[row * 4 + l16] = v;
                else er[row * 4 + (l16 - 4)] = v;
            }
        }
    }

    unsigned short* scr = Bs + wm * 1536;
    int half = lane >> 5, l32 = lane & 31;
    int rrow = l32 >> 1, coff = (l32 & 1) * 8;
#pragma unroll
    for (int mf = 0; mf < 2; ++mf) {
#pragma unroll
        for (int p = 0; p < 8; ++p) {
            unsigned short* base = scr + (p & 1) * 768;
#pragma unroll
            for (int fr = 0; fr < 2; ++fr) {
                int nf = 2 * p + fr;
                unsigned short* fb = base + fr * 384;
#pragma unroll
                for (int r = 0; r < 4; ++r)
                    fb[(quad * 4 + r) * 24 + l16] = f2b(acc[mf][nf][r]);
            }
            uint4 val = *(const uint4*)(base + half * 384 + rrow * 24 + coff);
            int row = m0 + wm * 32 + mf * 16 + rrow;
            int nf = 2 * p + half;
            if (row < N_NODES) {
                float f0 = blo(val.x), f1 = bhi(val.x), f2 = blo(val.y), f3 = bhi(val.y);
                float f4 = blo(val.z), f5 = bhi(val.z), f6 = blo(val.w), f7 = bhi(val.w);
                int lo = __builtin_amdgcn_cvt_pk_fp8_f32(f0, f1, 0, 0);
                lo = __builtin_amdgcn_cvt_pk_fp8_f32(f2, f3, lo, 1);
                int hi = __builtin_amdgcn_cvt_pk_fp8_f32(f4, f5, 0, 0);
                hi = __builtin_amdgcn_cvt_pk_fp8_f32(f6, f7, hi, 1);
                uint2 o;
                o.x = (unsigned int)lo;
                o.y = (unsigned int)hi;
                *(uint2*)&C[(size_t)row * 256 + nf * 16 + coff] = o;
            }
        }
    }
}

// ---------------- P3: per-bucket LDS node presort -> coalesced csr_src + row_ptr ----------------
__global__ __launch_bounds__(256) void p3_kernel(const int* __restrict__ partial,
                                                 const int* __restrict__ bsum,
                                                 const unsigned int* __restrict__ ebuf,
                                                 int* __restrict__ row_ptr,
                                                 int* __restrict__ csr_src) {
    __shared__ int wsum[4];
    __shared__ int sb[256];
    __shared__ int lcnt[256];
    __shared__ int lfill[256];
    __shared__ int sorted[MAXB];
    int b = blockIdx.x, t = threadIdx.x;
    int lane = t & 63, w = t >> 6;
    {
        int v = (t < NSCB) ? bsum[t] : 0;
        int incl = v;
#pragma unroll
        for (int off = 1; off < 64; off <<= 1) {
            int x = __shfl_up(incl, off);
            if (lane >= off) incl += x;
        }
        if (lane == 63) wsum[w] = incl;
        __syncthreads();
        int woff = 0;
        for (int k = 0; k < w; ++k) woff += wsum[k];
        sb[t] = woff + incl - v;
    }
    __syncthreads();
    int i0 = b * NBLK;
    int base = partial[i0] + sb[i0 >> 10];
    int endb;
    if (b == NBUCK - 1) endb = N_EDGES;
    else {
        int i1 = (b + 1) * NBLK;
        endb = partial[i1] + sb[i1 >> 10];
    }
    lcnt[t] = 0;
    __syncthreads();
    for (int i = base + t; i < endb; i += 256)
        atomicAdd(&lcnt[ebuf[i] & 255u], 1);
    __syncthreads();
    {
        int v = lcnt[t];
        int incl = v;
#pragma unroll
        for (int off = 1; off < 64; off <<= 1) {
            int x = __shfl_up(incl, off);
            if (lane >= off) incl += x;
        }
        if (lane == 63) wsum[w] = incl;
        __syncthreads();
        int woff = 0;
        for (int k = 0; k < w; ++k) woff += wsum[k];
        int excl = woff + incl - v;
        lfill[t] = excl;
        int node = b * 256 + t;
        if (node < NP1) row_ptr[node] = base + excl;
    }
    __syncthreads();
    for (int i = base + t; i < endb; i += 256) {
        unsigned int p = ebuf[i];
        int pos = atomicAdd(&lfill[p & 255u], 1);
        sorted[pos] = (int)(p >> 16);
    }
    __syncthreads();
    int M = endb - base;
    for (int i = t; i < M; i += 256)
        csr_src[base + i] = sorted[i];
}

// ---------------- layer-1 aggregation: 4 nodes/wave, no cross-lane reduce, 2-deep ----------------
// (R5's proven configuration: 2-deep keeps VGPR ~36 and occupancy high; agg1 is traffic-
// bound at ~2.9 TB/s on its gather pattern, so deeper unroll measured zero gain at an
// occupancy cost — R6.) Each 16-lane group owns node n and its FULL 256B feat row.
__global__ void agg1_kernel(const unsigned char* __restrict__ feat1,
                            const float* __restrict__ el, const float* __restrict__ er,
                            const int* __restrict__ row_ptr, const int* __restrict__ csr_src,
                            const float* __restrict__ b1, unsigned short* __restrict__ h1b) {
    int wave = threadIdx.x >> 6, lane = threadIdx.x & 63;
    int q = lane >> 4, l16 = lane & 15;
    int n = (blockIdx.x * 4 + wave) * 4 + q;      // 16 nodes per block
    bool vn = n < N_NODES;
    int h = l16 >> 2;
    int start = 0, end = 0;
    if (vn) {
        start = row_ptr[n];
        end = row_ptr[n + 1];
    }
    float er_h = vn ? er[n * 4 + h] : 0.f;

    floatx2 acc2[8];
#pragma unroll
    for (int j = 0; j < 8; ++j) acc2[j] = (floatx2){0.f, 0.f};
    float denom = 0.f;

    int i = start;
    for (; i + 1 < end; i += 2) {
        int s0 = csr_src[i];
        int s1 = csr_src[i + 1];
        float e0 = __expf(leaky(el[s0 * 4 + h] + er_h));
        float e1 = __expf(leaky(el[s1 * 4 + h] + er_h));
        uint4 a = *(const uint4*)(feat1 + (size_t)s0 * 256 + l16 * 16);
        uint4 b = *(const uint4*)(feat1 + (size_t)s1 * 256 + l16 * 16);
        denom += e0 + e1;
        fp8acc2(a, (floatx2){e0, e0}, acc2);
        fp8acc2(b, (floatx2){e1, e1}, acc2);
    }
    if (i < end) {
        int s = csr_src[i];
        float e = __expf(leaky(el[s * 4 + h] + er_h));
        uint4 u = *(const uint4*)(feat1 + (size_t)s * 256 + l16 * 16);
        denom += e;
        fp8acc2(u, (floatx2){e, e}, acc2);
    }
    if (!vn) return;

    float inv = (end > start) ? 1.f / denom : 0.f;
    float o[16];
#pragma unroll
    for (int j = 0; j < 8; ++j) {
        o[2 * j] = acc2[j][0];
        o[2 * j + 1] = acc2[j][1];
    }
#pragma unroll
    for (int j = 0; j < 16; j += 4) {
        float4 b4 = *(const float4*)&b1[l16 * 16 + j];
        o[j + 0] = fmaf(o[j + 0], inv, b4.x);
        o[j + 1] = fmaf(o[j + 1], inv, b4.y);
        o[j + 2] = fmaf(o[j + 2], inv, b4.z);
        o[j + 3] = fmaf(o[j + 3], inv, b4.w);
    }
#pragma unroll
    for (int j = 0; j < 16; ++j) o[j] = o[j] > 0.f ? o[j] : __expf(o[j]) - 1.f;
    uint4 pa, pb;
    pa.x = pack2(o[0], o[1]);   pa.y = pack2(o[2], o[3]);
    pa.z = pack2(o[4], o[5]);   pa.w = pack2(o[6], o[7]);
    pb.x = pack2(o[8], o[9]);   pb.y = pack2(o[10], o[11]);
    pb.z = pack2(o[12], o[13]); pb.w = pack2(o[14], o[15]);
    uint4* dstp = (uint4*)(h1b + (size_t)n * 256 + l16 * 16);
    dstp[0] = pa;
    dstp[1] = pb;
}

// ---------------- GEMM2 (bf16 MFMA, no LDS) + fused el2/er2, bf16 feat2 out ----------------
__global__ __launch_bounds__(256) void gemm2_mfma_kernel(
        const unsigned short* __restrict__ h1b, const unsigned short* __restrict__ W2T,
        const float* __restrict__ al2, const float* __restrict__ ar2,
        unsigned short* __restrict__ feat2b, float* __restrict__ el2, float* __restrict__ er2) {
    int wave = threadIdx.x >> 6, lane = threadIdx.x & 63;
    int l16 = lane & 15, quad = lane >> 4;
    int row0 = (blockIdx.x * 4 + wave) * 16;
    if (row0 >= N_NODES) return;
    floatx4 acc = (floatx4){0.f, 0.f, 0.f, 0.f};
    const unsigned short* arow = h1b + (size_t)(row0 + l16) * 256 + quad * 8;
    const unsigned short* brow = W2T + (size_t)l16 * 256 + quad * 8;
#pragma unroll
    for (int k0 = 0; k0 < 256; k0 += 32) {
        short8 a = *(const short8*)(arow + k0);
        short8 b = *(const short8*)(brow + k0);
        acc = __builtin_amdgcn_mfma_f32_16x16x32_bf16(a, b, acc, 0, 0, 0);
    }
    float a2 = al2[l16], r2 = ar2[l16];
#pragma unroll
    for (int r = 0; r < 4; ++r) {
        int row = row0 + quad * 4 + r;
        float v = acc[r];
        feat2b[row * 16 + l16] = f2b(v);
        float pl = v * a2, pr = v * r2;
#pragma unroll
        for (int off = 1; off < 16; off <<= 1) {
            pl += __shfl_xor(pl, off);
            pr += __shfl_xor(pr, off);
        }
        if (l16 == 0) {
            el2[row] = pl;
            er2[row] = pr;
        }
    }
}

// ---------------- layer-2 aggregation + log_softmax: 4 nodes/wave, 4-deep ----------------
// agg2's gather table (feat2b, 1.6MB) is L2-resident per XCD -> latency-bound regime,
// so deeper sequential unroll is the right lever here (unlike agg1). 4-deep body is two
// consecutive 2-deep bodies (identical load/denom/fma order) -> bit-identical numerics.
__global__ void agg2_kernel(const unsigned short* __restrict__ feat2b,
                            const float* __restrict__ el2, const float* __restrict__ er2,
                            const int* __restrict__ row_ptr, const int* __restrict__ csr_src,
                            const float* __restrict__ b2, float* __restrict__ out) {
    int wave = threadIdx.x >> 6, lane = threadIdx.x & 63;
    int q = lane >> 4, c = lane & 15;
    int n = (blockIdx.x * 4 + wave) * 4 + q;      // 16 nodes per block
    if (n >= N_NODES) return;
    int start = row_ptr[n], end = row_ptr[n + 1];
    float ern = er2[n];
    float acc = 0.f, denom = 0.f;
    int i = start;
    for (; i + 3 < end; i += 4) {
        int s0 = csr_src[i], s1 = csr_src[i + 1];
        int s2 = csr_src[i + 2], s3 = csr_src[i + 3];
        float e0 = __expf(leaky(el2[s0] + ern));
        float e1 = __expf(leaky(el2[s1] + ern));
        float e2 = __expf(leaky(el2[s2] + ern));
        float e3 = __expf(leaky(el2[s3] + ern));
        float f0 = b2f(feat2b[s0 * 16 + c]), f1 = b2f(feat2b[s1 * 16 + c]);
        float f2 = b2f(feat2b[s2 * 16 + c]), f3 = b2f(feat2b[s3 * 16 + c]);
        denom += e0 + e1;
        denom += e2 + e3;
        acc = fmaf(f0, e0, acc);
        acc = fmaf(f1, e1, acc);
        acc = fmaf(f2, e2, acc);
        acc = fmaf(f3, e3, acc);
    }
    for (; i + 1 < end; i += 2) {
        int s0 = csr_src[i], s1 = csr_src[i + 1];
        float e0 = __expf(leaky(el2[s0] + ern));
        float e1 = __expf(leaky(el2[s1] + ern));
        float f0 = b2f(feat2b[s0 * 16 + c]), f1 = b2f(feat2b[s1 * 16 + c]);
        denom += e0 + e1;
        acc = fmaf(f0, e0, acc);
        acc = fmaf(f1, e1, acc);
    }
    if (i < end) {
        int s = csr_src[i];
        float e = __expf(leaky(el2[s] + ern));
        denom += e;
        acc = fmaf(b2f(feat2b[s * 16 + c]), e, acc);
    }
    float v = ((end > start) ? acc / denom : 0.f) + b2[c];
    float mx = v;
#pragma unroll
    for (int off = 1; off < 16; off <<= 1) mx = fmaxf(mx, __shfl_xor(mx, off));
    float ex2 = __expf(v - mx);
    float s2v = ex2;
#pragma unroll
    for (int off = 1; off < 16; off <<= 1) s2v += __shfl_xor(s2v, off);
    float res = v - mx - logf(s2v);
    out[n * 16 + c] = res;
}

// ---------------- launch ----------------
extern "C" void kernel_launch(void* const* d_in, const int* in_sizes, int n_in,
                              void* d_out, int out_size, void* d_ws, size_t ws_size,
                              hipStream_t stream) {
    const float* x   = (const float*)d_in[0];
    const int*   src = (const int*)d_in[1];
    const int*   dst = (const int*)d_in[2];
    const float* W1  = (const float*)d_in[3];
    const float* al1 = (const float*)d_in[4];
    const float* ar1 = (const float*)d_in[5];
    const float* b1  = (const float*)d_in[6];
    const float* W2  = (const float*)d_in[7];
    const float* al2 = (const float*)d_in[8];
    const float* ar2 = (const float*)d_in[9];
    const float* b2  = (const float*)d_in[10];
    float* out = (float*)d_out;

    char* ws = (char*)d_ws;
    size_t off = 0;
    auto alloc = [&](size_t bytes) -> void* {
        void* p = ws + off;
        off += (bytes + 255) & ~(size_t)255;
        return p;
    };
    unsigned short* W1E    = (unsigned short*)alloc((size_t)272 * 256 * 2);
    unsigned short* W2T    = (unsigned short*)alloc((size_t)16 * 256 * 2);
    unsigned char*  feat1  = (unsigned char*)alloc((size_t)N_NODES * 256);
    unsigned short* h1b    = (unsigned short*)alloc((size_t)N_NODES * 256 * 2);
    unsigned short* feat2b = (unsigned short*)alloc((size_t)N_NODES * 16 * 2);
    float* el1     = (float*)alloc((size_t)N_NODES * 4 * 4);
    float* er1     = (float*)alloc((size_t)N_NODES * 4 * 4);
    float* el2     = (float*)alloc((size_t)N_NODES * 4);
    float* er2     = (float*)alloc((size_t)N_NODES * 4);
    int*   bhist   = (int*)alloc((size_t)NSCAN * 4);
    int*   partial = (int*)alloc((size_t)NSCAN * 4);
    int*   bsum    = (int*)alloc((size_t)256 * 4);
    int*   row_ptr = (int*)alloc((size_t)NP1 * 4);
    unsigned int* ebuf = (unsigned int*)alloc((size_t)N_EDGES * 4);
    int*   csr_src = (int*)alloc((size_t)N_EDGES * 4);

    dim3 b256(256);
    p1_kernel<<<NBLK + 21, b256, 0, stream>>>(dst, bhist, W1, W2, al1, ar1, W1E, W2T);
    scanA_kernel<<<NSCB, b256, 0, stream>>>(bhist, partial, bsum);
    p2g1_kernel<<<NGB + NBLK, b256, 0, stream>>>(src, dst, partial, bsum, ebuf,
                                                 x, W1E, feat1, el1, er1);
    p3_kernel<<<NBUCK, b256, 0, stream>>>(partial, bsum, ebuf, row_ptr, csr_src);

    agg1_kernel<<<(N_NODES + 15) / 16, b256, 0, stream>>>(feat1, el1, er1, row_ptr, csr_src, b1, h1b);

    gemm2_mfma_kernel<<<(N_NODES + 63) / 64, b256, 0, stream>>>(h1b, W2T, al2, ar2, feat2b, el2, er2);
    agg2_kernel<<<(N_NODES + 15) / 16, b256, 0, stream>>>(feat2b, el2, er2, row_ptr, csr_src, b2, out);
}

// Round 9
// 228.562 us; speedup vs baseline: 1.0396x; 1.0206x over previous
//
#include <hip/hip_runtime.h>
#include <hip/hip_bf16.h>

#define N_NODES 50000
#define NP1     50001
#define N_EDGES 800000
#define NFEAT   256
#define NHID    64
#define HEADS   4
#define NCLASS  16
#define NEG_SLOPE 0.2f

#define NBLK  782                 // edge blocks (1024 edges each)
#define NBUCK 196                 // buckets of 256 nodes (dst >> 8)
#define NSCAN (NBUCK * NBLK)      // 153272
#define NSCB  150                 // ceil(NSCAN / 1024)
#define MAXB  5120                // max edges per bucket (avg 4096)
#define NGB   391                 // gemm1 blocks: (N_NODES+127)/128 ; also X-convert blocks

typedef __attribute__((ext_vector_type(8))) short short8;
typedef __attribute__((ext_vector_type(4))) float floatx4;
typedef __attribute__((ext_vector_type(2))) float floatx2;

__device__ __forceinline__ float blo(unsigned int u) { return __uint_as_float(u << 16); }
__device__ __forceinline__ float bhi(unsigned int u) { return __uint_as_float(u & 0xffff0000u); }
__device__ __forceinline__ float b2f(unsigned short u) {
    return __uint_as_float(((unsigned int)u) << 16);
}
__device__ __forceinline__ unsigned short f2b(float f) {
    unsigned int x = __float_as_uint(f);
    unsigned int r = x + 0x7fffu + ((x >> 16) & 1u);
    return (unsigned short)(r >> 16);
}
__device__ __forceinline__ unsigned int pack2(float a, float b) {
    return (unsigned int)f2b(a) | ((unsigned int)f2b(b) << 16);
}
__device__ __forceinline__ float leaky(float x) { return fmaxf(x, NEG_SLOPE * x); }

// fp8 unpack + packed-fp32 accumulate: 8 cvt_pk + 8 v_pk_fma_f32 per 16 features
__device__ __forceinline__ void fp8acc2(uint4 u, floatx2 exv, floatx2* acc) {
    acc[0] = __builtin_elementwise_fma(__builtin_amdgcn_cvt_pk_f32_fp8(u.x, 0), exv, acc[0]);
    acc[1] = __builtin_elementwise_fma(__builtin_amdgcn_cvt_pk_f32_fp8(u.x, 1), exv, acc[1]);
    acc[2] = __builtin_elementwise_fma(__builtin_amdgcn_cvt_pk_f32_fp8(u.y, 0), exv, acc[2]);
    acc[3] = __builtin_elementwise_fma(__builtin_amdgcn_cvt_pk_f32_fp8(u.y, 1), exv, acc[3]);
    acc[4] = __builtin_elementwise_fma(__builtin_amdgcn_cvt_pk_f32_fp8(u.z, 0), exv, acc[4]);
    acc[5] = __builtin_elementwise_fma(__builtin_amdgcn_cvt_pk_f32_fp8(u.z, 1), exv, acc[5]);
    acc[6] = __builtin_elementwise_fma(__builtin_amdgcn_cvt_pk_f32_fp8(u.w, 0), exv, acc[6]);
    acc[7] = __builtin_elementwise_fma(__builtin_amdgcn_cvt_pk_f32_fp8(u.w, 1), exv, acc[7]);
}

// ---------------- P1: per-block bucket histogram + fused weight prep + X->bf16 convert ----------------
// blocks [0, NBLK): dst histogram; [NBLK, NBLK+21): weight prep; [NBLK+21, NBLK+21+NGB): X convert.
__global__ __launch_bounds__(256) void p1_kernel(
        const int* __restrict__ dst, int* __restrict__ bhist,
        const float* __restrict__ W1, const float* __restrict__ W2,
        const float* __restrict__ al1, const float* __restrict__ ar1,
        unsigned short* __restrict__ W1E, unsigned short* __restrict__ W2T,
        const float* __restrict__ X, unsigned short* __restrict__ Xb) {
    __shared__ float tile[64][65];
    __shared__ int hist[NBUCK];
    int b = blockIdx.x, t = threadIdx.x;
    if (b < NBLK) {
        if (t < NBUCK) hist[t] = 0;
        __syncthreads();
        int e = (b * 256 + t) * 4;
        if (e < N_EDGES) {
            int4 d = *(const int4*)&dst[e];
            atomicAdd(&hist[d.x >> 8], 1);
            atomicAdd(&hist[d.y >> 8], 1);
            atomicAdd(&hist[d.z >> 8], 1);
            atomicAdd(&hist[d.w >> 8], 1);
        }
        __syncthreads();
        if (t < NBUCK) bhist[t * NBLK + b] = hist[t];
        return;
    }
    int pb = b - NBLK;
    if (pb < 16) {
        int tk = (pb & 3) * 64, tn = (pb >> 2) * 64;
        int tx = t & 63, ty = t >> 6;
#pragma unroll
        for (int r = 0; r < 16; ++r) {
            int row = ty * 16 + r;
            tile[row][tx] = W1[(tk + row) * 256 + tn + tx];
        }
        __syncthreads();
#pragma unroll
        for (int r = 0; r < 16; ++r) {
            int row = ty * 16 + r;
            W1E[(tn + row) * 256 + tk + tx] = f2b(tile[tx][row]);
        }
    } else if (pb < 20) {
        int h = pb - 16;
        int w = t >> 6, lane = t & 63;
        float alv = al1[h * 64 + lane];
        float arv = ar1[h * 64 + lane];
        for (int k = w; k < 256; k += 4) {
            float wv = W1[k * 256 + h * 64 + lane];
            float sl = wv * alv, sr = wv * arv;
#pragma unroll
            for (int off = 1; off < 64; off <<= 1) {
                sl += __shfl_xor(sl, off);
                sr += __shfl_xor(sr, off);
            }
            if (lane == 0) {
                W1E[(256 + h) * 256 + k] = f2b(sl);
                W1E[(260 + h) * 256 + k] = f2b(sr);
            }
        }
    } else if (pb < 21) {
        int n = t >> 4, k0 = (t & 15) * 16;
#pragma unroll
        for (int j = 0; j < 16; ++j)
            W2T[n * 256 + k0 + j] = f2b(W2[(k0 + j) * 16 + n]);
#pragma unroll
        for (int j = 0; j < 8; ++j)
            W1E[264 * 256 + j * 256 + t] = 0;
    } else {
        // X -> bf16 convert: block covers 128 rows; identical f2b values as the old
        // in-gemm1 conversion -> gemm1 MFMA sees identical bits. Rows >= N zeroed.
        int cb = pb - 21;
        int r0 = cb * 128;
        int rsub = t >> 6;          // 0..3
        int c4 = (t & 63) * 4;      // col (x4 floats)
        for (int rr = 0; rr < 128; rr += 4) {
            int row = r0 + rr + rsub;
            uint2 o;
            if (row < N_NODES) {
                float4 v = *(const float4*)&X[(size_t)row * 256 + c4];
                o.x = pack2(v.x, v.y);
                o.y = pack2(v.z, v.w);
            } else {
                o.x = 0; o.y = 0;
            }
            *(uint2*)&Xb[(size_t)row * 256 + c4] = o;
        }
    }
}

// ---------------- scanA: per-chunk (1024) exclusive scan of bhist ----------------
__global__ __launch_bounds__(256) void scanA_kernel(const int* __restrict__ bhist,
                                                    int* __restrict__ partial,
                                                    int* __restrict__ bsum) {
    __shared__ int wsum[4];
    int t = threadIdx.x;
    int base = blockIdx.x * 1024 + t * 4;
    int v0 = (base + 0 < NSCAN) ? bhist[base + 0] : 0;
    int v1 = (base + 1 < NSCAN) ? bhist[base + 1] : 0;
    int v2 = (base + 2 < NSCAN) ? bhist[base + 2] : 0;
    int v3 = (base + 3 < NSCAN) ? bhist[base + 3] : 0;
    int s = v0 + v1 + v2 + v3;
    int lane = t & 63, w = t >> 6;
    int incl = s;
#pragma unroll
    for (int off = 1; off < 64; off <<= 1) {
        int x = __shfl_up(incl, off);
        if (lane >= off) incl += x;
    }
    if (lane == 63) wsum[w] = incl;
    __syncthreads();
    int woff = 0;
    for (int k = 0; k < w; ++k) woff += wsum[k];
    int excl = woff + incl - s;
    if (base + 0 < NSCAN) partial[base + 0] = excl;
    if (base + 1 < NSCAN) partial[base + 1] = excl + v0;
    if (base + 2 < NSCAN) partial[base + 2] = excl + v0 + v1;
    if (base + 3 < NSCAN) partial[base + 3] = excl + v0 + v1 + v2;
    if (t == 255) bsum[blockIdx.x] = woff + incl;
}

// ---------------- P2+GEMM1 merged dispatch ----------------
// blocks [0, NGB): gemm1 (MFMA-heavy);  blocks [NGB, NGB+NBLK): p2 edge presort
__global__ __launch_bounds__(256, 2) void p2g1_kernel(
        const int* __restrict__ src, const int* __restrict__ dst,
        const int* __restrict__ partial, const int* __restrict__ bsum,
        unsigned int* __restrict__ ebuf,
        const unsigned short* __restrict__ Xb, const unsigned short* __restrict__ BT,
        unsigned char* __restrict__ C, float* __restrict__ el, float* __restrict__ er) {
    // gemm1 LDS
    __shared__ __align__(16) unsigned short As[128 * 40];
    __shared__ __align__(16) unsigned short Bs[272 * 40];
    // p2 LDS
    __shared__ int wsum[4];
    __shared__ int sb[256];
    __shared__ int bs[NBUCK];
    __shared__ int lcnt[256];
    __shared__ int lofs[256];
    __shared__ int lfill[256];
    __shared__ unsigned int sorted[1024];

    int t = threadIdx.x;
    if (blockIdx.x >= NGB) {
        // ---- p2: LDS bucket presort ----
        int b = blockIdx.x - NGB;
        int lane = t & 63, w = t >> 6;
        {
            int v = (t < NSCB) ? bsum[t] : 0;
            int incl = v;
#pragma unroll
            for (int off = 1; off < 64; off <<= 1) {
                int x = __shfl_up(incl, off);
                if (lane >= off) incl += x;
            }
            if (lane == 63) wsum[w] = incl;
            __syncthreads();
            int woff = 0;
            for (int k = 0; k < w; ++k) woff += wsum[k];
            sb[t] = woff + incl - v;
        }
        lcnt[t] = 0;
        __syncthreads();
        if (t < NBUCK) {
            int idx = t * NBLK + b;
            bs[t] = partial[idx] + sb[idx >> 10];
        }
        int e = (b * 256 + t) * 4;
        int4 d, s;
        bool valid = e < N_EDGES;
        if (valid) {
            d = *(const int4*)&dst[e];
            s = *(const int4*)&src[e];
            atomicAdd(&lcnt[d.x >> 8], 1);
            atomicAdd(&lcnt[d.y >> 8], 1);
            atomicAdd(&lcnt[d.z >> 8], 1);
            atomicAdd(&lcnt[d.w >> 8], 1);
        }
        __syncthreads();
        {
            int v = lcnt[t];
            int incl = v;
#pragma unroll
            for (int off = 1; off < 64; off <<= 1) {
                int x = __shfl_up(incl, off);
                if (lane >= off) incl += x;
            }
            if (lane == 63) wsum[w] = incl;
            __syncthreads();
            int woff = 0;
            for (int k = 0; k < w; ++k) woff += wsum[k];
            int excl = woff + incl - v;
            lofs[t] = excl;
            lfill[t] = excl;
        }
        __syncthreads();
        if (valid) {
            int p0 = atomicAdd(&lfill[d.x >> 8], 1);
            sorted[p0] = ((unsigned int)s.x << 16) | (unsigned int)d.x;
            int p1 = atomicAdd(&lfill[d.y >> 8], 1);
            sorted[p1] = ((unsigned int)s.y << 16) | (unsigned int)d.y;
            int p2 = atomicAdd(&lfill[d.z >> 8], 1);
            sorted[p2] = ((unsigned int)s.z << 16) | (unsigned int)d.z;
            int p3 = atomicAdd(&lfill[d.w >> 8], 1);
            sorted[p3] = ((unsigned int)s.w << 16) | (unsigned int)d.w;
        }
        __syncthreads();
        int ve = min(1024, N_EDGES - b * 1024);
        for (int i = t; i < ve; i += 256) {
            unsigned int p = sorted[i];
            int k = (p & 0xFFFFu) >> 8;
            ebuf[bs[k] + (i - lofs[k])] = p;
        }
        return;
    }

    // ---- gemm1: [feat1(fp8) | el | er] = Xb @ [W1 | Wel | Wer] ----
    // A-staging is now a pure 16B x2 copy from preconverted bf16 Xb (no f2b packs,
    // no row guard — Xb covers all NGB*128 rows, tail zeroed).
    int m0 = blockIdx.x * 128;
    int lane = t & 63, wm = t >> 6;
    int quad = lane >> 4, l16 = lane & 15;

    floatx4 acc[2][17];
#pragma unroll
    for (int i = 0; i < 2; ++i)
#pragma unroll
        for (int j = 0; j < 17; ++j) acc[i][j] = (floatx4){0.f, 0.f, 0.f, 0.f};

    int arow = t >> 1, ak = (t & 1) * 16;
    const unsigned short* xrow = Xb + (size_t)(m0 + arow) * 256 + ak;

    for (int k0 = 0; k0 < 256; k0 += 32) {
        uint4 q0 = *(const uint4*)(xrow + k0);
        uint4 q1 = *(const uint4*)(xrow + k0 + 8);
        *(uint4*)&As[arow * 40 + ak] = q0;
        *(uint4*)&As[arow * 40 + ak + 8] = q1;
#pragma unroll
        for (int i = 0; i < 5; ++i) {
            int ch = t + i * 256;
            if (ch < 1088) {
                int row = ch >> 2, off = (ch & 3) * 8;
                *(uint4*)&Bs[row * 40 + off] = *(const uint4*)(BT + row * 256 + k0 + off);
            }
        }
        __syncthreads();

        short8 a0 = *(const short8*)&As[(wm * 32 + l16) * 40 + quad * 8];
        short8 a1 = *(const short8*)&As[(wm * 32 + 16 + l16) * 40 + quad * 8];
#pragma unroll
        for (int nf = 0; nf < 17; ++nf) {
            short8 bb = *(const short8*)&Bs[(nf * 16 + l16) * 40 + quad * 8];
            acc[0][nf] = __builtin_amdgcn_mfma_f32_16x16x32_bf16(a0, bb, acc[0][nf], 0, 0, 0);
            acc[1][nf] = __builtin_amdgcn_mfma_f32_16x16x32_bf16(a1, bb, acc[1][nf], 0, 0, 0);
        }
        __syncthreads();
    }

#pragma unroll
    for (int mf = 0; mf < 2; ++mf) {
#pragma unroll
        for (int r = 0; r < 4; ++r) {
            int row = m0 + wm * 32 + mf * 16 + quad * 4 + r;
            if (row < N_NODES && l16 < 8) {
                float v = acc[mf][16][r];
                if (l16 < 4) el[row * 4 + l16] = v;
                else er[row * 4 + (l16 - 4)] = v;
            }
        }
    }

    unsigned short* scr = Bs + wm * 1536;
    int half = lane >> 5, l32 = lane & 31;
    int rrow = l32 >> 1, coff = (l32 & 1) * 8;
#pragma unroll
    for (int mf = 0; mf < 2; ++mf) {
#pragma unroll
        for (int p = 0; p < 8; ++p) {
            unsigned short* base = scr + (p & 1) * 768;
#pragma unroll
            for (int fr = 0; fr < 2; ++fr) {
                int nf = 2 * p + fr;
                unsigned short* fb = base + fr * 384;
#pragma unroll
                for (int r = 0; r < 4; ++r)
                    fb[(quad * 4 + r) * 24 + l16] = f2b(acc[mf][nf][r]);
            }
            uint4 val = *(const uint4*)(base + half * 384 + rrow * 24 + coff);
            int row = m0 + wm * 32 + mf * 16 + rrow;
            int nf = 2 * p + half;
            if (row < N_NODES) {
                float f0 = blo(val.x), f1 = bhi(val.x), f2 = blo(val.y), f3 = bhi(val.y);
                float f4 = blo(val.z), f5 = bhi(val.z), f6 = blo(val.w), f7 = bhi(val.w);
                int lo = __builtin_amdgcn_cvt_pk_fp8_f32(f0, f1, 0, 0);
                lo = __builtin_amdgcn_cvt_pk_fp8_f32(f2, f3, lo, 1);
                int hi = __builtin_amdgcn_cvt_pk_fp8_f32(f4, f5, 0, 0);
                hi = __builtin_amdgcn_cvt_pk_fp8_f32(f6, f7, hi, 1);
                uint2 o;
                o.x = (unsigned int)lo;
                o.y = (unsigned int)hi;
                *(uint2*)&C[(size_t)row * 256 + nf * 16 + coff] = o;
            }
        }
    }
}

// ---------------- P3: per-bucket LDS node presort -> coalesced csr_src + row_ptr ----------------
__global__ __launch_bounds__(256) void p3_kernel(const int* __restrict__ partial,
                                                 const int* __restrict__ bsum,
                                                 const unsigned int* __restrict__ ebuf,
                                                 int* __restrict__ row_ptr,
                                                 int* __restrict__ csr_src) {
    __shared__ int wsum[4];
    __shared__ int sb[256];
    __shared__ int lcnt[256];
    __shared__ int lfill[256];
    __shared__ int sorted[MAXB];
    int b = blockIdx.x, t = threadIdx.x;
    int lane = t & 63, w = t >> 6;
    {
        int v = (t < NSCB) ? bsum[t] : 0;
        int incl = v;
#pragma unroll
        for (int off = 1; off < 64; off <<= 1) {
            int x = __shfl_up(incl, off);
            if (lane >= off) incl += x;
        }
        if (lane == 63) wsum[w] = incl;
        __syncthreads();
        int woff = 0;
        for (int k = 0; k < w; ++k) woff += wsum[k];
        sb[t] = woff + incl - v;
    }
    __syncthreads();
    int i0 = b * NBLK;
    int base = partial[i0] + sb[i0 >> 10];
    int endb;
    if (b == NBUCK - 1) endb = N_EDGES;
    else {
        int i1 = (b + 1) * NBLK;
        endb = partial[i1] + sb[i1 >> 10];
    }
    lcnt[t] = 0;
    __syncthreads();
    for (int i = base + t; i < endb; i += 256)
        atomicAdd(&lcnt[ebuf[i] & 255u], 1);
    __syncthreads();
    {
        int v = lcnt[t];
        int incl = v;
#pragma unroll
        for (int off = 1; off < 64; off <<= 1) {
            int x = __shfl_up(incl, off);
            if (lane >= off) incl += x;
        }
        if (lane == 63) wsum[w] = incl;
        __syncthreads();
        int woff = 0;
        for (int k = 0; k < w; ++k) woff += wsum[k];
        int excl = woff + incl - v;
        lfill[t] = excl;
        int node = b * 256 + t;
        if (node < NP1) row_ptr[node] = base + excl;
    }
    __syncthreads();
    for (int i = base + t; i < endb; i += 256) {
        unsigned int p = ebuf[i];
        int pos = atomicAdd(&lfill[p & 255u], 1);
        sorted[pos] = (int)(p >> 16);
    }
    __syncthreads();
    int M = endb - base;
    for (int i = t; i < M; i += 256)
        csr_src[base + i] = sorted[i];
}

// ---------------- layer-1 aggregation: 4 nodes/wave, no cross-lane reduce, 2-deep ----------------
// (R5's proven configuration: agg1 is traffic-bound at ~2.9 TB/s on its gather pattern.)
__global__ void agg1_kernel(const unsigned char* __restrict__ feat1,
                            const float* __restrict__ el, const float* __restrict__ er,
                            const int* __restrict__ row_ptr, const int* __restrict__ csr_src,
                            const float* __restrict__ b1, unsigned short* __restrict__ h1b) {
    int wave = threadIdx.x >> 6, lane = threadIdx.x & 63;
    int q = lane >> 4, l16 = lane & 15;
    int n = (blockIdx.x * 4 + wave) * 4 + q;      // 16 nodes per block
    bool vn = n < N_NODES;
    int h = l16 >> 2;
    int start = 0, end = 0;
    if (vn) {
        start = row_ptr[n];
        end = row_ptr[n + 1];
    }
    float er_h = vn ? er[n * 4 + h] : 0.f;

    floatx2 acc2[8];
#pragma unroll
    for (int j = 0; j < 8; ++j) acc2[j] = (floatx2){0.f, 0.f};
    float denom = 0.f;

    int i = start;
    for (; i + 1 < end; i += 2) {
        int s0 = csr_src[i];
        int s1 = csr_src[i + 1];
        float e0 = __expf(leaky(el[s0 * 4 + h] + er_h));
        float e1 = __expf(leaky(el[s1 * 4 + h] + er_h));
        uint4 a = *(const uint4*)(feat1 + (size_t)s0 * 256 + l16 * 16);
        uint4 b = *(const uint4*)(feat1 + (size_t)s1 * 256 + l16 * 16);
        denom += e0 + e1;
        fp8acc2(a, (floatx2){e0, e0}, acc2);
        fp8acc2(b, (floatx2){e1, e1}, acc2);
    }
    if (i < end) {
        int s = csr_src[i];
        float e = __expf(leaky(el[s * 4 + h] + er_h));
        uint4 u = *(const uint4*)(feat1 + (size_t)s * 256 + l16 * 16);
        denom += e;
        fp8acc2(u, (floatx2){e, e}, acc2);
    }
    if (!vn) return;

    float inv = (end > start) ? 1.f / denom : 0.f;
    float o[16];
#pragma unroll
    for (int j = 0; j < 8; ++j) {
        o[2 * j] = acc2[j][0];
        o[2 * j + 1] = acc2[j][1];
    }
#pragma unroll
    for (int j = 0; j < 16; j += 4) {
        float4 b4 = *(const float4*)&b1[l16 * 16 + j];
        o[j + 0] = fmaf(o[j + 0], inv, b4.x);
        o[j + 1] = fmaf(o[j + 1], inv, b4.y);
        o[j + 2] = fmaf(o[j + 2], inv, b4.z);
        o[j + 3] = fmaf(o[j + 3], inv, b4.w);
    }
#pragma unroll
    for (int j = 0; j < 16; ++j) o[j] = o[j] > 0.f ? o[j] : __expf(o[j]) - 1.f;
    uint4 pa, pb;
    pa.x = pack2(o[0], o[1]);   pa.y = pack2(o[2], o[3]);
    pa.z = pack2(o[4], o[5]);   pa.w = pack2(o[6], o[7]);
    pb.x = pack2(o[8], o[9]);   pb.y = pack2(o[10], o[11]);
    pb.z = pack2(o[12], o[13]); pb.w = pack2(o[14], o[15]);
    uint4* dstp = (uint4*)(h1b + (size_t)n * 256 + l16 * 16);
    dstp[0] = pa;
    dstp[1] = pb;
}

// ---------------- GEMM2 (bf16 MFMA, no LDS) + fused el2/er2, bf16 feat2 out ----------------
__global__ __launch_bounds__(256) void gemm2_mfma_kernel(
        const unsigned short* __restrict__ h1b, const unsigned short* __restrict__ W2T,
        const float* __restrict__ al2, const float* __restrict__ ar2,
        unsigned short* __restrict__ feat2b, float* __restrict__ el2, float* __restrict__ er2) {
    int wave = threadIdx.x >> 6, lane = threadIdx.x & 63;
    int l16 = lane & 15, quad = lane >> 4;
    int row0 = (blockIdx.x * 4 + wave) * 16;
    if (row0 >= N_NODES) return;
    floatx4 acc = (floatx4){0.f, 0.f, 0.f, 0.f};
    const unsigned short* arow = h1b + (size_t)(row0 + l16) * 256 + quad * 8;
    const unsigned short* brow = W2T + (size_t)l16 * 256 + quad * 8;
#pragma unroll
    for (int k0 = 0; k0 < 256; k0 += 32) {
        short8 a = *(const short8*)(arow + k0);
        short8 b = *(const short8*)(brow + k0);
        acc = __builtin_amdgcn_mfma_f32_16x16x32_bf16(a, b, acc, 0, 0, 0);
    }
    float a2 = al2[l16], r2 = ar2[l16];
#pragma unroll
    for (int r = 0; r < 4; ++r) {
        int row = row0 + quad * 4 + r;
        float v = acc[r];
        feat2b[row * 16 + l16] = f2b(v);
        float pl = v * a2, pr = v * r2;
#pragma unroll
        for (int off = 1; off < 16; off <<= 1) {
            pl += __shfl_xor(pl, off);
            pr += __shfl_xor(pr, off);
        }
        if (l16 == 0) {
            el2[row] = pl;
            er2[row] = pr;
        }
    }
}

// ---------------- layer-2 aggregation + log_softmax: 4 nodes/wave, 4-deep ----------------
__global__ void agg2_kernel(const unsigned short* __restrict__ feat2b,
                            const float* __restrict__ el2, const float* __restrict__ er2,
                            const int* __restrict__ row_ptr, const int* __restrict__ csr_src,
                            const float* __restrict__ b2, float* __restrict__ out) {
    int wave = threadIdx.x >> 6, lane = threadIdx.x & 63;
    int q = lane >> 4, c = lane & 15;
    int n = (blockIdx.x * 4 + wave) * 4 + q;      // 16 nodes per block
    if (n >= N_NODES) return;
    int start = row_ptr[n], end = row_ptr[n + 1];
    float ern = er2[n];
    float acc = 0.f, denom = 0.f;
    int i = start;
    for (; i + 3 < end; i += 4) {
        int s0 = csr_src[i], s1 = csr_src[i + 1];
        int s2 = csr_src[i + 2], s3 = csr_src[i + 3];
        float e0 = __expf(leaky(el2[s0] + ern));
        float e1 = __expf(leaky(el2[s1] + ern));
        float e2 = __expf(leaky(el2[s2] + ern));
        float e3 = __expf(leaky(el2[s3] + ern));
        float f0 = b2f(feat2b[s0 * 16 + c]), f1 = b2f(feat2b[s1 * 16 + c]);
        float f2 = b2f(feat2b[s2 * 16 + c]), f3 = b2f(feat2b[s3 * 16 + c]);
        denom += e0 + e1;
        denom += e2 + e3;
        acc = fmaf(f0, e0, acc);
        acc = fmaf(f1, e1, acc);
        acc = fmaf(f2, e2, acc);
        acc = fmaf(f3, e3, acc);
    }
    for (; i + 1 < end; i += 2) {
        int s0 = csr_src[i], s1 = csr_src[i + 1];
        float e0 = __expf(leaky(el2[s0] + ern));
        float e1 = __expf(leaky(el2[s1] + ern));
        float f0 = b2f(feat2b[s0 * 16 + c]), f1 = b2f(feat2b[s1 * 16 + c]);
        denom += e0 + e1;
        acc = fmaf(f0, e0, acc);
        acc = fmaf(f1, e1, acc);
    }
    if (i < end) {
        int s = csr_src[i];
        float e = __expf(leaky(el2[s] + ern));
        denom += e;
        acc = fmaf(b2f(feat2b[s * 16 + c]), e, acc);
    }
    float v = ((end > start) ? acc / denom : 0.f) + b2[c];
    float mx = v;
#pragma unroll
    for (int off = 1; off < 16; off <<= 1) mx = fmaxf(mx, __shfl_xor(mx, off));
    float ex2 = __expf(v - mx);
    float s2v = ex2;
#pragma unroll
    for (int off = 1; off < 16; off <<= 1) s2v += __shfl_xor(s2v, off);
    float res = v - mx - logf(s2v);
    out[n * 16 + c] = res;
}

// ---------------- launch ----------------
extern "C" void kernel_launch(void* const* d_in, const int* in_sizes, int n_in,
                              void* d_out, int out_size, void* d_ws, size_t ws_size,
                              hipStream_t stream) {
    const float* x   = (const float*)d_in[0];
    const int*   src = (const int*)d_in[1];
    const int*   dst = (const int*)d_in[2];
    const float* W1  = (const float*)d_in[3];
    const float* al1 = (const float*)d_in[4];
    const float* ar1 = (const float*)d_in[5];
    const float* b1  = (const float*)d_in[6];
    const float* W2  = (const float*)d_in[7];
    const float* al2 = (const float*)d_in[8];
    const float* ar2 = (const float*)d_in[9];
    const float* b2  = (const float*)d_in[10];
    float* out = (float*)d_out;

    char* ws = (char*)d_ws;
    size_t off = 0;
    auto alloc = [&](size_t bytes) -> void* {
        void* p = ws + off;
        off += (bytes + 255) & ~(size_t)255;
        return p;
    };
    unsigned short* W1E    = (unsigned short*)alloc((size_t)272 * 256 * 2);
    unsigned short* W2T    = (unsigned short*)alloc((size_t)16 * 256 * 2);
    unsigned char*  feat1  = (unsigned char*)alloc((size_t)N_NODES * 256);
    unsigned short* h1b    = (unsigned short*)alloc((size_t)N_NODES * 256 * 2);
    unsigned short* feat2b = (unsigned short*)alloc((size_t)N_NODES * 16 * 2);
    float* el1     = (float*)alloc((size_t)N_NODES * 4 * 4);
    float* er1     = (float*)alloc((size_t)N_NODES * 4 * 4);
    float* el2     = (float*)alloc((size_t)N_NODES * 4);
    float* er2     = (float*)alloc((size_t)N_NODES * 4);
    int*   bhist   = (int*)alloc((size_t)NSCAN * 4);
    int*   partial = (int*)alloc((size_t)NSCAN * 4);
    int*   bsum    = (int*)alloc((size_t)256 * 4);
    int*   row_ptr = (int*)alloc((size_t)NP1 * 4);
    unsigned int* ebuf = (unsigned int*)alloc((size_t)N_EDGES * 4);
    int*   csr_src = (int*)alloc((size_t)N_EDGES * 4);
    unsigned short* Xb = (unsigned short*)alloc((size_t)NGB * 128 * 256 * 2);  // 25.6MB bf16 X

    dim3 b256(256);
    p1_kernel<<<NBLK + 21 + NGB, b256, 0, stream>>>(dst, bhist, W1, W2, al1, ar1, W1E, W2T, x, Xb);
    scanA_kernel<<<NSCB, b256, 0, stream>>>(bhist, partial, bsum);
    p2g1_kernel<<<NGB + NBLK, b256, 0, stream>>>(src, dst, partial, bsum, ebuf,
                                                 Xb, W1E, feat1, el1, er1);
    p3_kernel<<<NBUCK, b256, 0, stream>>>(partial, bsum, ebuf, row_ptr, csr_src);

    agg1_kernel<<<(N_NODES + 15) / 16, b256, 0, stream>>>(feat1, el1, er1, row_ptr, csr_src, b1, h1b);

    gemm2_mfma_kernel<<<(N_NODES + 63) / 64, b256, 0, stream>>>(h1b, W2T, al2, ar2, feat2b, el2, er2);
    agg2_kernel<<<(N_NODES + 15) / 16, b256, 0, stream>>>(feat2b, el2, er2, row_ptr, csr_src, b2, out);
}